// Round 1
// baseline (445.385 us; speedup 1.0000x reference)
//
#include <hip/hip_runtime.h>

// Keys bicubic a=-0.5, jax.image.resize semantics:
//   sample = (i+0.5)*(n_in/n_out) - 0.5
//   weights over taps floor(sample)-1 .. floor(sample)+2, OOB taps dropped,
//   remaining weights renormalized to sum 1 (matches jax's weight-matrix
//   normalization; NOT clamp-replicate).
__device__ __forceinline__ void taps4(int i, int n, float inv, int idx[4], float w[4]) {
  float s = ((float)i + 0.5f) * inv - 0.5f;
  int k0 = (int)floorf(s);
  float sum = 0.f;
#pragma unroll
  for (int t = 0; t < 4; ++t) {
    int j = k0 - 1 + t;
    float d = fabsf(s - (float)j);
    float wt = (d <= 1.f) ? (((1.5f * d - 2.5f) * d) * d + 1.f)
                          : (((-0.5f * d + 2.5f) * d - 4.f) * d + 2.f);
    if (j < 0 || j >= n) wt = 0.f;
    idx[t] = (j < 0) ? 0 : ((j >= n) ? n - 1 : j);
    w[t] = wt;
    sum += wt;
  }
  float r = 1.f / sum;
#pragma unroll
  for (int t = 0; t < 4; ++t) w[t] *= r;
}

// One thread per output pixel: bicubic 2x upsample of `in` [B,n_in,n_in],
// fused with h = relu(wv[0]*up + wv[1]*cam + bv[0]).
__global__ void up2_fuse_kernel(const float* __restrict__ in, int n_in,
                                const float* __restrict__ cam,
                                const float* __restrict__ wv,
                                const float* __restrict__ bv,
                                float* __restrict__ out) {
  const int n_out = n_in * 2;
  int x = blockIdx.x * 64 + threadIdx.x;
  int y = blockIdx.y * 4 + threadIdx.y;
  int b = blockIdx.z;
  if (x >= n_out || y >= n_out) return;

  int ix[4], iy[4];
  float wx[4], wy[4];
  taps4(x, n_in, 0.5f, ix, wx);
  taps4(y, n_in, 0.5f, iy, wy);

  const float* img = in + (size_t)b * n_in * n_in;
  float acc = 0.f;
#pragma unroll
  for (int t = 0; t < 4; ++t) {
    const float* row = img + (size_t)iy[t] * n_in;
    acc += wy[t] * (wx[0] * row[ix[0]] + wx[1] * row[ix[1]] +
                    wx[2] * row[ix[2]] + wx[3] * row[ix[3]]);
  }
  size_t o = ((size_t)b * n_out + y) * n_out + x;
  float h = wv[0] * acc + wv[1] * cam[o] + bv[0];
  out[o] = fmaxf(h, 0.f);
}

// Final: 4x bicubic up 256->1024 of h256 [64,256,256], batch-flipped read.
// Each thread computes 4 consecutive output columns (one float4).
// Interior horizontal weights are compile-time constants (phases r=0..3 of
// sample = 0.25*x - 0.375):
//   r0 over cols gx-2..gx+1 : W0
//   r1 over cols gx-2..gx+1 : W1
//   r2 over cols gx-1..gx+2 : reverse(W1)
//   r3 over cols gx-1..gx+2 : reverse(W0)
#define W0_0 (-0.0439453125f)
#define W0_1 ( 0.3896484375f)
#define W0_2 ( 0.7275390625f)
#define W0_3 (-0.0732421875f)
#define W1_0 (-0.0068359375f)
#define W1_1 ( 0.0908203125f)
#define W1_2 ( 0.9638671875f)
#define W1_3 (-0.0478515625f)

__global__ void __launch_bounds__(256) up4_final_kernel(const float* __restrict__ in,
                                                        float* __restrict__ out) {
  const int N_IN = 256, N_OUT = 1024, B = 64;
  int gx = blockIdx.x * 64 + threadIdx.x;   // column group: outputs 4*gx..4*gx+3
  int y  = blockIdx.y * 4 + threadIdx.y;    // output row
  int b  = blockIdx.z;

  int iy[4];
  float wy[4];
  taps4(y, N_IN, 0.25f, iy, wy);

  const float* img = in + (size_t)(B - 1 - b) * N_IN * N_IN;  // batch flip

  // Load 4 rows x 5 cols, vertical blend into v[0..4] (cols gx-2..gx+2).
  int c0 = gx - 2;
  float v[5];
#pragma unroll
  for (int c = 0; c < 5; ++c) {
    int col = c0 + c;
    col = (col < 0) ? 0 : ((col >= N_IN) ? N_IN - 1 : col);
    float acc = 0.f;
#pragma unroll
    for (int t = 0; t < 4; ++t)
      acc += wy[t] * img[(size_t)iy[t] * N_IN + col];
    v[c] = acc;
  }

  float4 o;
  if (gx >= 2 && gx < N_IN - 2) {
    o.x = W0_0 * v[0] + W0_1 * v[1] + W0_2 * v[2] + W0_3 * v[3];
    o.y = W1_0 * v[0] + W1_1 * v[1] + W1_2 * v[2] + W1_3 * v[3];
    o.z = W1_3 * v[1] + W1_2 * v[2] + W1_1 * v[3] + W1_0 * v[4];
    o.w = W0_3 * v[1] + W0_2 * v[2] + W0_1 * v[3] + W0_0 * v[4];
  } else {
    // Border: generic renormalized weights. Tap t of output r maps to
    // v[t + (r>=2)] (same clamping as v[] construction; OOB weights are 0).
    float res[4];
#pragma unroll
    for (int r = 0; r < 4; ++r) {
      int x = 4 * gx + r;
      int ix[4];
      float wx[4];
      taps4(x, N_IN, 0.25f, ix, wx);
      int off = (r < 2) ? 0 : 1;
      res[r] = wx[0] * v[off] + wx[1] * v[off + 1] + wx[2] * v[off + 2] + wx[3] * v[off + 3];
    }
    o.x = res[0]; o.y = res[1]; o.z = res[2]; o.w = res[3];
  }

  *(float4*)(out + ((size_t)b * N_OUT + y) * N_OUT + 4 * gx) = o;
}

extern "C" void kernel_launch(void* const* d_in, const int* in_sizes, int n_in_,
                              void* d_out, int out_size, void* d_ws, size_t ws_size,
                              hipStream_t stream) {
  const float* cam256 = (const float*)d_in[0];
  const float* cam128 = (const float*)d_in[1];
  const float* cam64  = (const float*)d_in[2];
  const float* cam32  = (const float*)d_in[3];
  const float* w1 = (const float*)d_in[4];
  const float* b1 = (const float*)d_in[5];
  const float* w2 = (const float*)d_in[6];
  const float* b2 = (const float*)d_in[7];
  const float* w3 = (const float*)d_in[8];
  const float* b3 = (const float*)d_in[9];
  float* out = (float*)d_out;

  const int B = 64;
  float* h64  = (float*)d_ws;                       // [64,64,64]    1 MiB
  float* h128 = h64 + (size_t)B * 64 * 64;          // [64,128,128]  4 MiB
  float* h256 = h128 + (size_t)B * 128 * 128;       // [64,256,256] 16 MiB

  dim3 blk(64, 4, 1);
  up2_fuse_kernel<<<dim3(1, 16, B), blk, 0, stream>>>(cam32, 32, cam64, w1, b1, h64);
  up2_fuse_kernel<<<dim3(2, 32, B), blk, 0, stream>>>(h64, 64, cam128, w2, b2, h128);
  up2_fuse_kernel<<<dim3(4, 64, B), blk, 0, stream>>>(h128, 128, cam256, w3, b3, h256);
  up4_final_kernel<<<dim3(4, 256, B), blk, 0, stream>>>(h256, out);
}

// Round 3
// 349.440 us; speedup vs baseline: 1.2746x; 1.2746x over previous
//
#include <hip/hip_runtime.h>

typedef float vfloat4 __attribute__((ext_vector_type(4)));

// Keys bicubic a=-0.5, jax.image.resize semantics:
//   sample = (i+0.5)*(n_in/n_out) - 0.5
//   taps floor(sample)-1 .. floor(sample)+2, OOB taps dropped, remaining
//   weights renormalized to sum 1.
__device__ __forceinline__ void taps4(int i, int n, float inv, int idx[4], float w[4]) {
  float s = ((float)i + 0.5f) * inv - 0.5f;
  int k0 = (int)floorf(s);
  float sum = 0.f;
#pragma unroll
  for (int t = 0; t < 4; ++t) {
    int j = k0 - 1 + t;
    float d = fabsf(s - (float)j);
    float wt = (d <= 1.f) ? (((1.5f * d - 2.5f) * d) * d + 1.f)
                          : (((-0.5f * d + 2.5f) * d - 4.f) * d + 2.f);
    if (j < 0 || j >= n) wt = 0.f;
    idx[t] = (j < 0) ? 0 : ((j >= n) ? n - 1 : j);
    w[t] = wt;
    sum += wt;
  }
  float r = 1.f / sum;
#pragma unroll
  for (int t = 0; t < 4; ++t) w[t] *= r;
}

// 4x-upscale interior phase weights (sample = 0.25*x - 0.375):
//   phase 0 over cols c-2..c+1: W0;  phase 1 over c-2..c+1: W1
//   phase 2 over c-1..c+2: reverse(W1);  phase 3 over c-1..c+2: reverse(W0)
#define W0_0 (-0.0439453125f)
#define W0_1 ( 0.3896484375f)
#define W0_2 ( 0.7275390625f)
#define W0_3 (-0.0732421875f)
#define W1_0 (-0.0068359375f)
#define W1_1 ( 0.0908203125f)
#define W1_2 ( 0.9638671875f)
#define W1_3 (-0.0478515625f)

// 2x-upscale interior phase weights (sample = 0.5*x - 0.25):
//   phase 0 over cols c-2..c+1: U;  phase 1 over c-1..c+2: reverse(U)
#define U_0 (-0.0234375f)
#define U_1 ( 0.2265625f)
#define U_2 ( 0.8671875f)
#define U_3 (-0.0703125f)

// Bicubic 2x upsample fused with relu(wv0*up + wv1*cam + b).
// One thread per INPUT cell (k,g) -> 2x2 output block, from 5x5 patch.
__global__ void __launch_bounds__(256) up2_fuse_v2(const float* __restrict__ in, int n,
                                                   const float* __restrict__ cam,
                                                   const float* __restrict__ wv,
                                                   const float* __restrict__ bv,
                                                   float* __restrict__ out) {
  int g = blockIdx.x * 64 + threadIdx.x;  // input col cell
  int k = blockIdx.y * 4 + threadIdx.y;   // input row cell
  if (g >= n || k >= n) return;
  int b = blockIdx.z;
  const int no = 2 * n;
  const float* img = in + (size_t)b * n * n;

  float f[5][5];
#pragma unroll
  for (int i = 0; i < 5; ++i) {
    int r = k - 2 + i; r = r < 0 ? 0 : (r > n - 1 ? n - 1 : r);
    const float* rp = img + (size_t)r * n;
#pragma unroll
    for (int c = 0; c < 5; ++c) {
      int cc = g - 2 + c; cc = cc < 0 ? 0 : (cc > n - 1 ? n - 1 : cc);
      f[i][c] = rp[cc];
    }
  }

  float o[2][2];
  if (g >= 2 && g <= n - 3 && k >= 2 && k <= n - 3) {
    float v0[5], v1[5];
#pragma unroll
    for (int c = 0; c < 5; ++c) {
      v0[c] = U_0 * f[0][c] + U_1 * f[1][c] + U_2 * f[2][c] + U_3 * f[3][c];
      v1[c] = U_3 * f[1][c] + U_2 * f[2][c] + U_1 * f[3][c] + U_0 * f[4][c];
    }
    o[0][0] = U_0 * v0[0] + U_1 * v0[1] + U_2 * v0[2] + U_3 * v0[3];
    o[0][1] = U_3 * v0[1] + U_2 * v0[2] + U_1 * v0[3] + U_0 * v0[4];
    o[1][0] = U_0 * v1[0] + U_1 * v1[1] + U_2 * v1[2] + U_3 * v1[3];
    o[1][1] = U_3 * v1[1] + U_2 * v1[2] + U_1 * v1[3] + U_0 * v1[4];
  } else {
#pragma unroll
    for (int p = 0; p < 2; ++p) {
      int iyy[4]; float wy[4];
      taps4(2 * k + p, n, 0.5f, iyy, wy);
      // p=0 -> taps k-2..k+1 (f rows 0..3); p=1 -> k-1..k+2 (f rows 1..4)
      float vv[5];
#pragma unroll
      for (int c = 0; c < 5; ++c)
        vv[c] = wy[0] * f[p][c] + wy[1] * f[p + 1][c] + wy[2] * f[p + 2][c] + wy[3] * f[p + 3][c];
#pragma unroll
      for (int q = 0; q < 2; ++q) {
        int ixx[4]; float wx[4];
        taps4(2 * g + q, n, 0.5f, ixx, wx);
        o[p][q] = wx[0] * vv[q] + wx[1] * vv[q + 1] + wx[2] * vv[q + 2] + wx[3] * vv[q + 3];
      }
    }
  }

  float c0 = wv[0], c1 = wv[1], cb = bv[0];
#pragma unroll
  for (int p = 0; p < 2; ++p) {
    size_t base = ((size_t)b * no + (2 * k + p)) * no + 2 * g;
    const float2 cm = *(const float2*)(cam + base);
    float2 r;
    r.x = fmaxf(c0 * o[p][0] + c1 * cm.x + cb, 0.f);
    r.y = fmaxf(c0 * o[p][1] + c1 * cm.y + cb, 0.f);
    *(float2*)(out + base) = r;
  }
}

// Final: 4x bicubic 256->1024 of h256 [64,256,256], batch-flipped read.
// One thread per INPUT cell (k,g) -> 4x4 output block, from 5x5 patch.
__global__ void __launch_bounds__(256) up4_final_v2(const float* __restrict__ in,
                                                    float* __restrict__ out) {
  const int N = 256, NO = 1024, B = 64;
  int g = blockIdx.x * 64 + threadIdx.x;  // 0..255
  int k = blockIdx.y * 4 + threadIdx.y;   // 0..255
  int b = blockIdx.z;
  const float* img = in + (size_t)(B - 1 - b) * N * N;  // batch flip

  float f[5][5];
#pragma unroll
  for (int i = 0; i < 5; ++i) {
    int r = k - 2 + i; r = r < 0 ? 0 : (r > N - 1 ? N - 1 : r);
    const float* rp = img + (size_t)r * N;
#pragma unroll
    for (int c = 0; c < 5; ++c) {
      int cc = g - 2 + c; cc = cc < 0 ? 0 : (cc > N - 1 ? N - 1 : cc);
      f[i][c] = rp[cc];
    }
  }

  float o[4][4];
  if (g >= 2 && g <= N - 3 && k >= 2 && k <= N - 3) {
    float vy[4][5];
#pragma unroll
    for (int c = 0; c < 5; ++c) {
      vy[0][c] = W0_0 * f[0][c] + W0_1 * f[1][c] + W0_2 * f[2][c] + W0_3 * f[3][c];
      vy[1][c] = W1_0 * f[0][c] + W1_1 * f[1][c] + W1_2 * f[2][c] + W1_3 * f[3][c];
      vy[2][c] = W1_3 * f[1][c] + W1_2 * f[2][c] + W1_1 * f[3][c] + W1_0 * f[4][c];
      vy[3][c] = W0_3 * f[1][c] + W0_2 * f[2][c] + W0_1 * f[3][c] + W0_0 * f[4][c];
    }
#pragma unroll
    for (int p = 0; p < 4; ++p) {
      o[p][0] = W0_0 * vy[p][0] + W0_1 * vy[p][1] + W0_2 * vy[p][2] + W0_3 * vy[p][3];
      o[p][1] = W1_0 * vy[p][0] + W1_1 * vy[p][1] + W1_2 * vy[p][2] + W1_3 * vy[p][3];
      o[p][2] = W1_3 * vy[p][1] + W1_2 * vy[p][2] + W1_1 * vy[p][3] + W1_0 * vy[p][4];
      o[p][3] = W0_3 * vy[p][1] + W0_2 * vy[p][2] + W0_1 * vy[p][3] + W0_0 * vy[p][4];
    }
  } else {
#pragma unroll
    for (int p = 0; p < 4; ++p) {
      int iyy[4]; float wy[4];
      taps4(4 * k + p, N, 0.25f, iyy, wy);
      int oy = (p < 2) ? 0 : 1;  // p<2 -> f rows 0..3; else 1..4
      float vv[5];
#pragma unroll
      for (int c = 0; c < 5; ++c)
        vv[c] = wy[0] * f[oy][c] + wy[1] * f[oy + 1][c] + wy[2] * f[oy + 2][c] + wy[3] * f[oy + 3][c];
#pragma unroll
      for (int q = 0; q < 4; ++q) {
        int ixx[4]; float wx[4];
        taps4(4 * g + q, N, 0.25f, ixx, wx);
        int ox = (q < 2) ? 0 : 1;
        o[p][q] = wx[0] * vv[ox] + wx[1] * vv[ox + 1] + wx[2] * vv[ox + 2] + wx[3] * vv[ox + 3];
      }
    }
  }

#pragma unroll
  for (int p = 0; p < 4; ++p) {
    vfloat4 vec = { o[p][0], o[p][1], o[p][2], o[p][3] };
    __builtin_nontemporal_store(vec, (vfloat4*)(out + ((size_t)b * NO + 4 * k + p) * NO + 4 * g));
  }
}

extern "C" void kernel_launch(void* const* d_in, const int* in_sizes, int n_in_,
                              void* d_out, int out_size, void* d_ws, size_t ws_size,
                              hipStream_t stream) {
  const float* cam256 = (const float*)d_in[0];
  const float* cam128 = (const float*)d_in[1];
  const float* cam64  = (const float*)d_in[2];
  const float* cam32  = (const float*)d_in[3];
  const float* w1 = (const float*)d_in[4];
  const float* b1 = (const float*)d_in[5];
  const float* w2 = (const float*)d_in[6];
  const float* b2 = (const float*)d_in[7];
  const float* w3 = (const float*)d_in[8];
  const float* b3 = (const float*)d_in[9];
  float* out = (float*)d_out;

  const int B = 64;
  float* h64  = (float*)d_ws;                       // [64,64,64]    1 MiB
  float* h128 = h64 + (size_t)B * 64 * 64;          // [64,128,128]  4 MiB
  float* h256 = h128 + (size_t)B * 128 * 128;       // [64,256,256] 16 MiB

  dim3 blk(64, 4, 1);
  up2_fuse_v2<<<dim3(1, 8, B),  blk, 0, stream>>>(cam32, 32, cam64, w1, b1, h64);
  up2_fuse_v2<<<dim3(1, 16, B), blk, 0, stream>>>(h64, 64, cam128, w2, b2, h128);
  up2_fuse_v2<<<dim3(2, 32, B), blk, 0, stream>>>(h128, 128, cam256, w3, b3, h256);
  up4_final_v2<<<dim3(4, 64, B), blk, 0, stream>>>(h256, out);
}

// Round 4
// 332.597 us; speedup vs baseline: 1.3391x; 1.0506x over previous
//
#include <hip/hip_runtime.h>

typedef float vfloat4 __attribute__((ext_vector_type(4)));

__device__ __forceinline__ int iclamp(int v, int lo, int hi) {
  return v < lo ? lo : (v > hi ? hi : v);
}

// Keys bicubic a=-0.5, jax.image.resize semantics: weights only (callers map
// taps to fixed f-row/col offsets). OOB taps dropped + renormalized.
__device__ __forceinline__ void taps4w(int i, int n, float inv, float w[4]) {
  float s = ((float)i + 0.5f) * inv - 0.5f;
  int k0 = (int)floorf(s);
  float sum = 0.f;
#pragma unroll
  for (int t = 0; t < 4; ++t) {
    int j = k0 - 1 + t;
    float d = fabsf(s - (float)j);
    float wt = (d <= 1.f) ? (((1.5f * d - 2.5f) * d) * d + 1.f)
                          : (((-0.5f * d + 2.5f) * d - 4.f) * d + 2.f);
    if (j < 0 || j >= n) wt = 0.f;
    w[t] = wt;
    sum += wt;
  }
  float r = 1.f / sum;
#pragma unroll
  for (int t = 0; t < 4; ++t) w[t] *= r;
}

// 4x interior phase weights (sample = 0.25*x - 0.375)
#define W0_0 (-0.0439453125f)
#define W0_1 ( 0.3896484375f)
#define W0_2 ( 0.7275390625f)
#define W0_3 (-0.0732421875f)
#define W1_0 (-0.0068359375f)
#define W1_1 ( 0.0908203125f)
#define W1_2 ( 0.9638671875f)
#define W1_3 (-0.0478515625f)
// 2x interior phase weights (sample = 0.5*x - 0.25)
#define U_0 (-0.0234375f)
#define U_1 ( 0.2265625f)
#define U_2 ( 0.8671875f)
#define U_3 (-0.0703125f)

// 2x2 outputs of bicubic 2x upsample for input cell (k,g), f = 5x5 patch
// (rows/cols k-2..k+2 / g-2..g+2, edge-clamped gather).
__device__ __forceinline__ void up2_cell(const float (&f)[5][5], int k, int g, int n,
                                         float (&o)[2][2]) {
  if (g >= 2 && g <= n - 3 && k >= 2 && k <= n - 3) {
    float v0[5], v1[5];
#pragma unroll
    for (int c = 0; c < 5; ++c) {
      v0[c] = U_0 * f[0][c] + U_1 * f[1][c] + U_2 * f[2][c] + U_3 * f[3][c];
      v1[c] = U_3 * f[1][c] + U_2 * f[2][c] + U_1 * f[3][c] + U_0 * f[4][c];
    }
    o[0][0] = U_0 * v0[0] + U_1 * v0[1] + U_2 * v0[2] + U_3 * v0[3];
    o[0][1] = U_3 * v0[1] + U_2 * v0[2] + U_1 * v0[3] + U_0 * v0[4];
    o[1][0] = U_0 * v1[0] + U_1 * v1[1] + U_2 * v1[2] + U_3 * v1[3];
    o[1][1] = U_3 * v1[1] + U_2 * v1[2] + U_1 * v1[3] + U_0 * v1[4];
  } else {
#pragma unroll
    for (int p = 0; p < 2; ++p) {
      float wy[4];
      taps4w(2 * k + p, n, 0.5f, wy);
      float vv[5];
#pragma unroll
      for (int c = 0; c < 5; ++c)
        vv[c] = wy[0] * f[p][c] + wy[1] * f[p + 1][c] + wy[2] * f[p + 2][c] + wy[3] * f[p + 3][c];
#pragma unroll
      for (int q = 0; q < 2; ++q) {
        float wx[4];
        taps4w(2 * g + q, n, 0.5f, wx);
        o[p][q] = wx[0] * vv[q] + wx[1] * vv[q + 1] + wx[2] * vv[q + 2] + wx[3] * vv[q + 3];
      }
    }
  }
}

// 4x4 outputs of bicubic 4x upsample for input cell (k,g), f = 5x5 patch.
__device__ __forceinline__ void up4_cell(const float (&f)[5][5], int k, int g, int n,
                                         float (&o)[4][4]) {
  if (g >= 2 && g <= n - 3 && k >= 2 && k <= n - 3) {
    float vy[4][5];
#pragma unroll
    for (int c = 0; c < 5; ++c) {
      vy[0][c] = W0_0 * f[0][c] + W0_1 * f[1][c] + W0_2 * f[2][c] + W0_3 * f[3][c];
      vy[1][c] = W1_0 * f[0][c] + W1_1 * f[1][c] + W1_2 * f[2][c] + W1_3 * f[3][c];
      vy[2][c] = W1_3 * f[1][c] + W1_2 * f[2][c] + W1_1 * f[3][c] + W1_0 * f[4][c];
      vy[3][c] = W0_3 * f[1][c] + W0_2 * f[2][c] + W0_1 * f[3][c] + W0_0 * f[4][c];
    }
#pragma unroll
    for (int p = 0; p < 4; ++p) {
      o[p][0] = W0_0 * vy[p][0] + W0_1 * vy[p][1] + W0_2 * vy[p][2] + W0_3 * vy[p][3];
      o[p][1] = W1_0 * vy[p][0] + W1_1 * vy[p][1] + W1_2 * vy[p][2] + W1_3 * vy[p][3];
      o[p][2] = W1_3 * vy[p][1] + W1_2 * vy[p][2] + W1_1 * vy[p][3] + W1_0 * vy[p][4];
      o[p][3] = W0_3 * vy[p][1] + W0_2 * vy[p][2] + W0_1 * vy[p][3] + W0_0 * vy[p][4];
    }
  } else {
#pragma unroll
    for (int p = 0; p < 4; ++p) {
      float wy[4];
      taps4w(4 * k + p, n, 0.25f, wy);
      int oy = (p < 2) ? 0 : 1;
      float vv[5];
#pragma unroll
      for (int c = 0; c < 5; ++c)
        vv[c] = wy[0] * f[oy][c] + wy[1] * f[oy + 1][c] + wy[2] * f[oy + 2][c] + wy[3] * f[oy + 3][c];
#pragma unroll
      for (int q = 0; q < 4; ++q) {
        float wx[4];
        taps4w(4 * g + q, n, 0.25f, wx);
        int ox = (q < 2) ? 0 : 1;
        o[p][q] = wx[0] * vv[ox] + wx[1] * vv[ox + 1] + wx[2] * vv[ox + 2] + wx[3] * vv[ox + 3];
      }
    }
  }
}

// One block = one 32-row h256 slab of one image: builds h64/h128/h256 windows
// in LDS (all halos contained), then writes the 128x1024 output slab of the
// batch-flipped final 4x upsample with NT float4 stores.
__global__ void __launch_bounds__(512, 4) fused_all(
    const float* __restrict__ cam256, const float* __restrict__ cam128,
    const float* __restrict__ cam64, const float* __restrict__ cam32,
    const float* __restrict__ w1, const float* __restrict__ b1,
    const float* __restrict__ w2, const float* __restrict__ b2,
    const float* __restrict__ w3, const float* __restrict__ b3,
    float* __restrict__ out) {
  __shared__ float s_h64[16 * 64];    //  4 KB
  __shared__ float s_h128[24 * 128];  // 12 KB
  __shared__ float s_h256[36 * 256];  // 36 KB

  const int tid = threadIdx.x;
  const int slab = blockIdx.x;  // 0..7
  const int b = blockIdx.y;     // 0..63
  const int s = slab * 32;      // h256 core rows [s, s+32)

  // Window row ranges (global coords). Each level covers the next level's
  // clamped 5-tap halo; verified max extents: h256 36 rows, h128 24, h64 16.
  const int r_lo = s - 2 < 0 ? 0 : s - 2, r_hi = s + 33 > 255 ? 255 : s + 33;
  const int kr0 = r_lo >> 1, kr1 = r_hi >> 1;
  const int h256_row0 = 2 * kr0;
  const int j_lo = kr0 - 2 < 0 ? 0 : kr0 - 2, j_hi = kr1 + 2 > 127 ? 127 : kr1 + 2;
  const int kj0 = j_lo >> 1, kj1 = j_hi >> 1;
  const int h128_row0 = 2 * kj0;
  const int m_lo = kj0 - 2 < 0 ? 0 : kj0 - 2, m_hi = kj1 + 2 > 63 ? 63 : kj1 + 2;
  const int km0 = m_lo >> 1, km1 = m_hi >> 1;
  const int h64_row0 = 2 * km0;

  const float w1_0 = w1[0], w1_1 = w1[1], b1_0 = b1[0];
  const float w2_0 = w2[0], w2_1 = w2[1], b2_0 = b2[0];
  const float w3_0 = w3[0], w3_1 = w3[1], b3_0 = b3[0];

  // ---- Phase A: h64 window from cam32 (global) + cam64 ----
  {
    const float* c32 = cam32 + (size_t)b * 32 * 32;
    const float* c64 = cam64 + (size_t)b * 64 * 64;
    const int nk = km1 - km0 + 1;
    for (int idx = tid; idx < nk * 32; idx += 512) {
      int k = km0 + (idx >> 5), g = idx & 31;
      float f[5][5];
#pragma unroll
      for (int i = 0; i < 5; ++i) {
        int r = iclamp(k - 2 + i, 0, 31);
#pragma unroll
        for (int c = 0; c < 5; ++c) f[i][c] = c32[r * 32 + iclamp(g - 2 + c, 0, 31)];
      }
      float o[2][2];
      up2_cell(f, k, g, 32, o);
#pragma unroll
      for (int p = 0; p < 2; ++p)
#pragma unroll
        for (int q = 0; q < 2; ++q) {
          int row = 2 * k + p, col = 2 * g + q;
          float h = w1_0 * o[p][q] + w1_1 * c64[row * 64 + col] + b1_0;
          s_h64[(row - h64_row0) * 64 + col] = fmaxf(h, 0.f);
        }
    }
  }
  __syncthreads();

  // ---- Phase B: h128 window from h64 (LDS) + cam128 ----
  {
    const float* c128 = cam128 + (size_t)b * 128 * 128;
    const int nk = kj1 - kj0 + 1;
    for (int idx = tid; idx < nk * 64; idx += 512) {
      int k = kj0 + (idx >> 6), g = idx & 63;
      float f[5][5];
#pragma unroll
      for (int i = 0; i < 5; ++i) {
        int r = iclamp(k - 2 + i, 0, 63) - h64_row0;
#pragma unroll
        for (int c = 0; c < 5; ++c) f[i][c] = s_h64[r * 64 + iclamp(g - 2 + c, 0, 63)];
      }
      float o[2][2];
      up2_cell(f, k, g, 64, o);
#pragma unroll
      for (int p = 0; p < 2; ++p)
#pragma unroll
        for (int q = 0; q < 2; ++q) {
          int row = 2 * k + p, col = 2 * g + q;
          float h = w2_0 * o[p][q] + w2_1 * c128[row * 128 + col] + b2_0;
          s_h128[(row - h128_row0) * 128 + col] = fmaxf(h, 0.f);
        }
    }
  }
  __syncthreads();

  // ---- Phase C: h256 window from h128 (LDS) + cam256 ----
  {
    const float* c256 = cam256 + (size_t)b * 256 * 256;
    const int nk = kr1 - kr0 + 1;
    for (int idx = tid; idx < nk * 128; idx += 512) {
      int k = kr0 + (idx >> 7), g = idx & 127;
      float f[5][5];
#pragma unroll
      for (int i = 0; i < 5; ++i) {
        int r = iclamp(k - 2 + i, 0, 127) - h128_row0;
#pragma unroll
        for (int c = 0; c < 5; ++c) f[i][c] = s_h128[r * 128 + iclamp(g - 2 + c, 0, 127)];
      }
      float o[2][2];
      up2_cell(f, k, g, 128, o);
#pragma unroll
      for (int p = 0; p < 2; ++p)
#pragma unroll
        for (int q = 0; q < 2; ++q) {
          int row = 2 * k + p, col = 2 * g + q;
          float h = w3_0 * o[p][q] + w3_1 * c256[row * 256 + col] + b3_0;
          s_h256[(row - h256_row0) * 256 + col] = fmaxf(h, 0.f);
        }
    }
  }
  __syncthreads();

  // ---- Phase D: final 4x upsample of h256 slab, batch-flipped output ----
  {
    float* outimg = out + (size_t)(63 - b) * 1024 * 1024;
    for (int idx = tid; idx < 32 * 256; idx += 512) {
      int k = s + (idx >> 8), g = idx & 255;
      float f[5][5];
#pragma unroll
      for (int i = 0; i < 5; ++i) {
        int r = iclamp(k - 2 + i, 0, 255) - h256_row0;
#pragma unroll
        for (int c = 0; c < 5; ++c) f[i][c] = s_h256[r * 256 + iclamp(g - 2 + c, 0, 255)];
      }
      float o[4][4];
      up4_cell(f, k, g, 256, o);
#pragma unroll
      for (int p = 0; p < 4; ++p) {
        vfloat4 v = {o[p][0], o[p][1], o[p][2], o[p][3]};
        __builtin_nontemporal_store(v, (vfloat4*)(outimg + (size_t)(4 * k + p) * 1024 + 4 * g));
      }
    }
  }
}

extern "C" void kernel_launch(void* const* d_in, const int* in_sizes, int n_in_,
                              void* d_out, int out_size, void* d_ws, size_t ws_size,
                              hipStream_t stream) {
  const float* cam256 = (const float*)d_in[0];
  const float* cam128 = (const float*)d_in[1];
  const float* cam64  = (const float*)d_in[2];
  const float* cam32  = (const float*)d_in[3];
  const float* w1 = (const float*)d_in[4];
  const float* b1 = (const float*)d_in[5];
  const float* w2 = (const float*)d_in[6];
  const float* b2 = (const float*)d_in[7];
  const float* w3 = (const float*)d_in[8];
  const float* b3 = (const float*)d_in[9];
  float* out = (float*)d_out;

  fused_all<<<dim3(8, 64), 512, 0, stream>>>(cam256, cam128, cam64, cam32,
                                             w1, b1, w2, b2, w3, b3, out);
}